// Round 1
// baseline (1174.579 us; speedup 1.0000x reference)
//
#include <hip/hip_runtime.h>
#include <float.h>
#include <math.h>

#define DIM    256
#define LEN    1024
#define KC     4096
#define NTOK   32768
#define TM     64      // tokens per block
#define TKC    256     // codes per K-tile
#define DCH    64      // D-chunk staged in LDS

// d_out float offsets (return order: loss, quantized, perplexity, embedding, indices, encodings)
#define O_LOSS 0
#define O_Q    1
#define O_PERP 8388609
#define O_EMB  8388610
#define O_IDX  9437186
#define O_ENC  9469954

// workspace float offsets
#define W_ET   0         // ET[D][K]            1048576 floats
#define W_CB   1048576   // 0.5*||e_k||^2       4096
#define W_CNT  1052672   // counts (int)        4096
#define W_BS   1056768   // per-block 2*score   512
#define W_SQ   1057280   // sumsq partials      256

// ---------------- E -> ET transpose (64x64 LDS tiles) ----------------
__global__ __launch_bounds__(256)
void k_transpose(const float* __restrict__ E, float* __restrict__ ET)
{
    __shared__ float T[64][65];
    const int tid = threadIdx.x;
    const int bk = blockIdx.x & 63;   // 64 K-tiles
    const int bd = blockIdx.x >> 6;   // 4 D-tiles
#pragma unroll
    for (int r = 0; r < 4; ++r) {
        int lin = r * 256 + tid;
        int row = lin >> 4;           // k-local
        int c4  = lin & 15;           // d-local float4
        float4 v = *(const float4*)(E + (size_t)(bk * 64 + row) * DIM + bd * 64 + c4 * 4);
        T[row][c4 * 4 + 0] = v.x;
        T[row][c4 * 4 + 1] = v.y;
        T[row][c4 * 4 + 2] = v.z;
        T[row][c4 * 4 + 3] = v.w;
    }
    __syncthreads();
#pragma unroll
    for (int r = 0; r < 4; ++r) {
        int lin  = r * 256 + tid;
        int drow = lin >> 4;          // d-local
        int c4   = lin & 15;          // k-local float4
        float4 v;
        v.x = T[c4 * 4 + 0][drow];
        v.y = T[c4 * 4 + 1][drow];
        v.z = T[c4 * 4 + 2][drow];
        v.w = T[c4 * 4 + 3][drow];
        *(float4*)(ET + (size_t)(bd * 64 + drow) * KC + bk * 64 + c4 * 4) = v;
    }
}

// ---------------- 0.5*||e_k||^2 ----------------
__global__ __launch_bounds__(256)
void k_cbias(const float* __restrict__ E, float* __restrict__ cb)
{
    const int tid = threadIdx.x;
    const int k   = blockIdx.x * 16 + (tid >> 4);
    const int ch  = tid & 15;
    const float* p = E + (size_t)k * DIM + ch * 16;
    float s = 0.f;
#pragma unroll
    for (int i = 0; i < 4; ++i) {
        float4 v = *(const float4*)(p + i * 4);
        s += v.x * v.x + v.y * v.y + v.z * v.z + v.w * v.w;
    }
#pragma unroll
    for (int m = 1; m < 16; m <<= 1) s += __shfl_xor(s, m, 64);
    if (ch == 0) cb[k] = 0.5f * s;
}

// ---------------- sum of squares of inputs ----------------
__global__ __launch_bounds__(256)
void k_sumsq(const float* __restrict__ X, float* __restrict__ outp)
{
    const int tid = threadIdx.x;
    const int blk = blockIdx.x;
    const float4* X4 = (const float4*)X;
    float s = 0.f;
#pragma unroll 4
    for (int i = 0; i < 32; ++i) {
        float4 v = X4[(size_t)i * 65536 + blk * 256 + tid];
        s += v.x * v.x + v.y * v.y + v.z * v.z + v.w * v.w;
    }
#pragma unroll
    for (int m = 1; m < 64; m <<= 1) s += __shfl_xor(s, m, 64);
    __shared__ float sp[4];
    if ((tid & 63) == 0) sp[tid >> 6] = s;
    __syncthreads();
    if (tid == 0) outp[blk] = sp[0] + sp[1] + sp[2] + sp[3];
}

// ---------------- main: distances + argmin + fused outputs ----------------
__global__ __launch_bounds__(256, 2)
void k_main(const float* __restrict__ X, const float* __restrict__ ET,
            const float* __restrict__ cb, const float* __restrict__ E,
            float* __restrict__ out, int* __restrict__ counts,
            float* __restrict__ bscore)
{
    __shared__ float4 Xs4[DCH * 16];   // [64 d][64 tok]  16 KB
    __shared__ float4 Es4[DCH * 64];   // [64 d][256 code] 64 KB

    const int tid  = threadIdx.x;
    const int trow = tid >> 4;         // token group (4 tokens)
    const int tcol = tid & 15;         // code group (16 codes: tcol*4 + g*64)
    const int n0   = blockIdx.x * TM;
    const int b    = n0 >> 10;
    const int l0   = n0 & (LEN - 1);
    const float* Xb = X + (size_t)b * DIM * LEN + l0;
    float* encB = out + (size_t)O_ENC + (size_t)n0 * KC;  // base ≡ 2 mod 4 floats -> float2 ops only

    float bestS[4] = {FLT_MAX, FLT_MAX, FLT_MAX, FLT_MAX};
    int   bestI[4] = {0, 0, 0, 0};

#pragma unroll 1
    for (int kt = 0; kt < KC / TKC; ++kt) {
        float acc[4][16];
#pragma unroll
        for (int i = 0; i < 4; ++i)
#pragma unroll
            for (int j = 0; j < 16; ++j) acc[i][j] = 0.f;

#pragma unroll 1
        for (int dt = 0; dt < 4; ++dt) {
            __syncthreads();
            {
                const float* gx = Xb + (size_t)(dt * DCH) * LEN;
#pragma unroll
                for (int r = 0; r < 4; ++r) {
                    int lin = r * 256 + tid;
                    Xs4[lin] = *(const float4*)(gx + (size_t)(lin >> 4) * LEN + (lin & 15) * 4);
                }
                const float* ge = ET + (size_t)(dt * DCH) * KC + kt * TKC;
#pragma unroll
                for (int r = 0; r < 16; ++r) {
                    int lin = r * 256 + tid;
                    Es4[lin] = *(const float4*)(ge + (size_t)(lin >> 6) * KC + (lin & 63) * 4);
                }
            }
            __syncthreads();
#pragma unroll 4
            for (int dc = 0; dc < DCH; ++dc) {
                float4 xv = Xs4[dc * 16 + trow];
                float4 e0 = Es4[dc * 64 + tcol];
                float4 e1 = Es4[dc * 64 + 16 + tcol];
                float4 e2 = Es4[dc * 64 + 32 + tcol];
                float4 e3 = Es4[dc * 64 + 48 + tcol];
                float xf[4], ef[16];
                *(float4*)(xf) = xv;
                *(float4*)(ef)      = e0;
                *(float4*)(ef + 4)  = e1;
                *(float4*)(ef + 8)  = e2;
                *(float4*)(ef + 12) = e3;
#pragma unroll
                for (int i = 0; i < 4; ++i)
#pragma unroll
                    for (int j = 0; j < 16; ++j)
                        acc[i][j] = fmaf(xf[i], ef[j], acc[i][j]);
            }
        }
        // score = 0.5*||e||^2 - x.e ; argmin (strict < keeps first/lowest k within thread)
        {
            const float* cbp = cb + kt * TKC + tcol * 4;
            float cf[16];
            *(float4*)(cf)      = *(const float4*)(cbp);
            *(float4*)(cf + 4)  = *(const float4*)(cbp + 64);
            *(float4*)(cf + 8)  = *(const float4*)(cbp + 128);
            *(float4*)(cf + 12) = *(const float4*)(cbp + 192);
            const int kb = kt * TKC + tcol * 4;
#pragma unroll
            for (int i = 0; i < 4; ++i)
#pragma unroll
                for (int j = 0; j < 16; ++j) {
                    float s = cf[j] - acc[i][j];
                    int k = kb + (j >> 2) * 64 + (j & 3);
                    if (s < bestS[i]) { bestS[i] = s; bestI[i] = k; }
                }
        }
        // interleaved zero-fill of this block's one-hot rows (hides 536MB write under compute)
        {
            float2 z2 = make_float2(0.f, 0.f);
#pragma unroll 4
            for (int r = 0; r < 32; ++r) {
                int lin = r * 256 + tid;   // float2 index within this kt chunk
                int t   = lin >> 7;        // token 0..63
                int c2  = lin & 127;
                *(float2*)(encB + (size_t)t * KC + kt * TKC + c2 * 2) = z2;
            }
        }
    }

    __syncthreads();                       // LDS compute done -> reuse Xs4 as scratch
    int*   ids   = (int*)Xs4;              // [64]
    float* wpart = ((float*)Xs4) + 64;     // [4]

    // cross-tcol argmin: packed (sortable score, idx) u64 min -> jnp.argmin tie semantics
    unsigned long long key[4];
#pragma unroll
    for (int i = 0; i < 4; ++i) {
        unsigned u = __float_as_uint(bestS[i]);
        u = (u & 0x80000000u) ? ~u : (u | 0x80000000u);
        key[i] = ((unsigned long long)u << 32) | (unsigned)bestI[i];
    }
#pragma unroll
    for (int m = 1; m < 16; m <<= 1)
#pragma unroll
        for (int i = 0; i < 4; ++i) {
            unsigned long long o = __shfl_xor(key[i], m, 64);
            key[i] = (o < key[i]) ? o : key[i];
        }

    float distSum = 0.f;
    if (tcol == 0) {
#pragma unroll
        for (int i = 0; i < 4; ++i) {
            int k = (int)(key[i] & 0xFFFFFFFFull);
            unsigned hu = (unsigned)(key[i] >> 32);
            hu = (hu & 0x80000000u) ? (hu ^ 0x80000000u) : ~hu;
            float s = __uint_as_float(hu);          // min score
            int n = n0 + trow * 4 + i;
            out[(size_t)O_IDX + n] = (float)k;
            atomicAdd(&counts[k], 1);
            ids[trow * 4 + i] = k;
            distSum += 2.f * s;                     // dist = 2*score + ||x||^2 (x^2 added later)
        }
    }
#pragma unroll
    for (int m = 1; m < 64; m <<= 1) distSum += __shfl_xor(distSum, m, 64);
    if ((tid & 63) == 0) wpart[tid >> 6] = distSum;
    __syncthreads();
    if (tid == 0) bscore[blockIdx.x] = wpart[0] + wpart[1] + wpart[2] + wpart[3];

    // fused quantized_st = x + (q - x), exact STE arithmetic, [B,D,L] layout
    {
        float* qb = out + (size_t)O_Q + (size_t)b * DIM * LEN + l0;
#pragma unroll 1
        for (int r = 0; r < 64; ++r) {
            int lin = r * 256 + tid;
            int d = lin >> 6;      // one d per wave-instr
            int t = lin & 63;
            float q = E[(size_t)ids[t] * DIM + d];
            float x = Xb[(size_t)d * LEN + t];
            qb[(size_t)d * LEN + t] = x + (q - x);
        }
    }
    // one-hot fixup (ordering vs zero-fill guaranteed by barrier's vmcnt drain)
    if (tid < TM) {
        int k = ids[tid];
        float2 v;
        v.x = (k & 1) ? 0.f : 1.f;
        v.y = (k & 1) ? 1.f : 0.f;
        *(float2*)(encB + (size_t)tid * KC + (k & ~1)) = v;
    }
}

// ---------------- scalars: loss + perplexity ----------------
__global__ __launch_bounds__(256)
void k_final(const float* __restrict__ bscore, const float* __restrict__ sumsq,
             const int* __restrict__ counts, float* __restrict__ out)
{
    const int tid = threadIdx.x;
    float s = bscore[tid] + bscore[tid + 256] + sumsq[tid];
    float h = 0.f;
#pragma unroll
    for (int i = 0; i < 16; ++i) {
        float p = (float)counts[tid * 16 + i] * (1.0f / 32768.f);
        h += p * logf(p + 1e-10f);
    }
#pragma unroll
    for (int m = 1; m < 64; m <<= 1) {
        s += __shfl_xor(s, m, 64);
        h += __shfl_xor(h, m, 64);
    }
    __shared__ float rs[4], rh[4];
    if ((tid & 63) == 0) { rs[tid >> 6] = s; rh[tid >> 6] = h; }
    __syncthreads();
    if (tid == 0) {
        float S = rs[0] + rs[1] + rs[2] + rs[3];
        float H = rh[0] + rh[1] + rh[2] + rh[3];
        out[O_LOSS] = 0.25f * S / 8388608.f;
        out[O_PERP] = expf(-H);
    }
}

extern "C" void kernel_launch(void* const* d_in, const int* in_sizes, int n_in,
                              void* d_out, int out_size, void* d_ws, size_t ws_size,
                              hipStream_t stream)
{
    (void)in_sizes; (void)n_in; (void)out_size; (void)ws_size;
    const float* X = (const float*)d_in[0];
    const float* E = (const float*)d_in[1];
    float* out = (float*)d_out;
    float* ws  = (float*)d_ws;
    float* ET     = ws + W_ET;
    float* cbias  = ws + W_CB;
    int*   counts = (int*)(ws + W_CNT);
    float* bscore = ws + W_BS;
    float* sumsq  = ws + W_SQ;

    hipMemsetAsync(counts, 0, KC * sizeof(int), stream);
    k_transpose<<<256, 256, 0, stream>>>(E, ET);
    k_cbias    <<<256, 256, 0, stream>>>(E, cbias);
    k_sumsq    <<<256, 256, 0, stream>>>(X, sumsq);
    k_main     <<<512, 256, 0, stream>>>(X, ET, cbias, E, out, counts, bscore);
    k_final    <<<1,   256, 0, stream>>>(bscore, sumsq, counts, out);
    hipMemcpyAsync(out + O_EMB, E, (size_t)KC * DIM * sizeof(float),
                   hipMemcpyDeviceToDevice, stream);
}